// Round 7
// baseline (327.504 us; speedup 1.0000x reference)
//
#include <hip/hip_runtime.h>
#include <stdint.h>

#define D_MODEL 1024
#define NH 16
#define DKK 64
#define SEQ 2048
// softmax scale folded into Q projection: 0.125 * log2(e)
#define QSCALE 0.18033688011112042f

using half8 = __attribute__((ext_vector_type(8))) _Float16;
using half4 = __attribute__((ext_vector_type(4))) _Float16;
using half2v = __attribute__((ext_vector_type(2))) _Float16;
using fp16x2 = __attribute__((ext_vector_type(2))) __fp16;
using f32x4 = __attribute__((ext_vector_type(4))) float;

__device__ __forceinline__ f32x4 fz4() { f32x4 v = {0.f, 0.f, 0.f, 0.f}; return v; }

// async global->LDS, 16B per lane; LDS dest = wave-uniform base + lane*16
__device__ __forceinline__ void gload16(const void* g, void* l) {
    __builtin_amdgcn_global_load_lds(
        (const __attribute__((address_space(1))) unsigned int*)g,
        (__attribute__((address_space(3))) unsigned int*)l, 16, 0, 0);
}

__device__ __forceinline__ half2v pk2(float a, float b) {
    fp16x2 t = __builtin_amdgcn_cvt_pkrtz(a, b);
    return __builtin_bit_cast(half2v, t);
}

__device__ __forceinline__ half4 pk4(float a, float b, float c, float d) {
    half2v lo = pk2(a, b);
    half2v hi = pk2(c, d);
    half4 r; r.x = lo.x; r.y = lo.y; r.z = hi.x; r.w = hi.y;
    return r;
}

// XCD-chunked swizzle
__device__ __forceinline__ int xswz(int bid, int n) {
    return (bid & 7) * (n >> 3) + (bid >> 3);
}

// ---------------- weights fp32 -> fp16: [WQ|WK|WV|WO] ----------------
__global__ __launch_bounds__(256) void conv_w(const float* __restrict__ wq,
                                              const float* __restrict__ wk,
                                              const float* __restrict__ wv,
                                              const float* __restrict__ wo,
                                              _Float16* __restrict__ out) {
    int idx = blockIdx.x * 256 + threadIdx.x;     // 2048 blocks -> 524288 threads
#pragma unroll
    for (int k = 0; k < 2; ++k) {
        int c = idx + k * 524288;                 // 1,048,576 float4 chunks
        int w = c >> 18;
        const float* src = (w == 0) ? wq : (w == 1) ? wk : (w == 2) ? wv : wo;
        float4 v = ((const float4*)src)[c & 0x3ffff];
        ((half4*)out)[c] = pk4(v.x, v.y, v.z, v.w);
    }
}

// ---------------- mask -> bitmask ----------------
__global__ __launch_bounds__(256) void pack_mask_k(const int* __restrict__ mask,
                                                   unsigned int* __restrict__ mbits) {
    int wid = threadIdx.x >> 6, lane = threadIdx.x & 63;
    int row = blockIdx.x * 4 + wid;
    const int* mrow = mask + (size_t)row * SEQ;
    unsigned int* orow = mbits + (size_t)row * (SEQ / 32);
    for (int it = 0; it < SEQ / 64; ++it) {
        int v = mrow[it * 64 + lane];
        unsigned long long bal = __ballot(v != 0);
        if (lane == 0)       orow[it * 2]     = (unsigned int)(bal & 0xffffffffull);
        else if (lane == 32) orow[it * 2 + 1] = (unsigned int)(bal >> 32);
    }
}

// ---------------- GEMM body: C[m][n] = A[m][:]·W[n][:] + bias[n] ----------------
// BM=64 BN=128 BK=64, dbuf LDS. B via global_load_lds (fp16 W, src pre-swizzled).
// AMODE 0: A fp32, reg-staged + convert (dest-swizzled). AMODE 1: A fp16 gload_lds.
template <int AMODE>
__device__ __forceinline__ void gemm_body(const void* __restrict__ Ap,
                                          const _Float16* __restrict__ Wh,
                                          const float* __restrict__ bias,
                                          void* __restrict__ outp, int omode, float scale) {
    __shared__ __align__(16) _Float16 Asm[2][64 * 64];
    __shared__ __align__(16) _Float16 Bsm[2][128 * 64];
    const int tid = threadIdx.x;
    const int wg = xswz(blockIdx.x, 512);
    const int bm = wg >> 3, bn = wg & 7;
    const int wid = tid >> 6, lane = tid & 63;
    const int li = lane & 15, g = lane >> 4;
    const int wm = wid >> 1, wn = wid & 1;

    const int brow = wid * 32 + (lane >> 3);
    const char* bsrc = (const char*)(Wh + (size_t)(bn * 128 + brow) * D_MODEL)
                       + (((lane & 7) ^ (brow & 7)) * 16);
    const int bdst = wid * 32 * 128;

    // AMODE 0 addressing (fp32 A, 16 floats/lane)
    const int arow0 = wid * 16 + (lane >> 2);
    const float* asrc4 = (const float*)Ap + (size_t)(bm * 64 + arow0) * D_MODEL + (lane & 3) * 16;
    const int awo0 = arow0 * 128 + (((lane & 3) * 32)      ^ ((arow0 & 7) << 4));
    const int awo1 = arow0 * 128 + (((lane & 3) * 32 + 16) ^ ((arow0 & 7) << 4));
    // AMODE 1 addressing (fp16 A via gload_lds)
    const int arow1 = wid * 16 + (lane >> 3);
    const char* asrc1 = (const char*)Ap + (size_t)(bm * 64 + arow1) * (D_MODEL * 2)
                        + (((lane & 7) ^ (arow1 & 7)) * 16);
    const int adst1 = wid * 16 * 128;

    f32x4 acc[2][4];
#pragma unroll
    for (int i = 0; i < 2; ++i)
#pragma unroll
        for (int j = 0; j < 4; ++j) acc[i][j] = fz4();

    const int o0 = ((g << 4))      ^ ((li & 7) << 4);
    const int o1 = (64 + (g << 4)) ^ ((li & 7) << 4);
    const int abase = wm * 4096 + li * 128;
    const int bbase = wn * 8192 + li * 128;

    auto stage = [&](int it, int buf) {
        const char* bs = bsrc + it * 128;
        char* bd = (char*)&Bsm[buf][0] + bdst;
        gload16(bs,             bd);
        gload16(bs +  8 * 2048, bd + 1024);
        gload16(bs + 16 * 2048, bd + 2048);
        gload16(bs + 24 * 2048, bd + 3072);
        if constexpr (AMODE == 0) {
            const float* s = asrc4 + it * 64;
            float4 v0 = *(const float4*)(s);
            float4 v1 = *(const float4*)(s + 4);
            float4 v2 = *(const float4*)(s + 8);
            float4 v3 = *(const float4*)(s + 12);
            char* d = (char*)&Asm[buf][0];
            half8 h0, h1;
            *(half4*)&h0 = pk4(v0.x, v0.y, v0.z, v0.w);
            *((half4*)&h0 + 1) = pk4(v1.x, v1.y, v1.z, v1.w);
            *(half4*)&h1 = pk4(v2.x, v2.y, v2.z, v2.w);
            *((half4*)&h1 + 1) = pk4(v3.x, v3.y, v3.z, v3.w);
            *(half8*)(d + awo0) = h0;
            *(half8*)(d + awo1) = h1;
        } else {
            const char* as = asrc1 + it * 128;
            char* ad = (char*)&Asm[buf][0] + adst1;
            gload16(as,            ad);
            gload16(as + 8 * 2048, ad + 1024);
        }
    };

    stage(0, 0);
    __syncthreads();

    for (int it = 0; it < 16; ++it) {
        const int cur = it & 1;
        if (it + 1 < 16) stage(it + 1, cur ^ 1);
        const char* ab = (const char*)&Asm[cur][0];
        const char* bb = (const char*)&Bsm[cur][0];
#pragma unroll
        for (int s = 0; s < 2; ++s) {
            const int oS = s ? o1 : o0;
            half8 af0 = *(const half8*)(ab + abase + 0    + oS);
            half8 af1 = *(const half8*)(ab + abase + 2048 + oS);
            half8 bf[4];
#pragma unroll
            for (int nt = 0; nt < 4; ++nt)
                bf[nt] = *(const half8*)(bb + bbase + nt * 2048 + oS);
#pragma unroll
            for (int nt = 0; nt < 4; ++nt) {
                acc[0][nt] = __builtin_amdgcn_mfma_f32_16x16x32_f16(af0, bf[nt], acc[0][nt], 0, 0, 0);
                acc[1][nt] = __builtin_amdgcn_mfma_f32_16x16x32_f16(af1, bf[nt], acc[1][nt], 0, 0, 0);
            }
        }
        __syncthreads();
    }

#pragma unroll
    for (int nt = 0; nt < 4; ++nt) {
        int n = bn * 128 + wn * 64 + nt * 16 + li;
        float bv = bias[n];
#pragma unroll
        for (int mt = 0; mt < 2; ++mt) {
            if (omode == 1) {
                int s0 = bm * 64 + wm * 32 + mt * 16 + g * 4;
                int b = (bm * 64) >> 11;
                int h = n >> 6, d = n & 63;
                half4 hv = pk4(acc[mt][nt][0] + bv, acc[mt][nt][1] + bv,
                               acc[mt][nt][2] + bv, acc[mt][nt][3] + bv);
                *(half4*)((_Float16*)outp +
                          ((((size_t)(b * NH + h)) * DKK + d) * SEQ + (s0 & (SEQ - 1)))) = hv;
            } else {
#pragma unroll
                for (int r = 0; r < 4; ++r) {
                    int m = bm * 64 + wm * 32 + mt * 16 + g * 4 + r;
                    float val = (acc[mt][nt][r] + bv) * scale;
                    if (omode == 2) {
                        ((float*)outp)[(size_t)m * D_MODEL + n] = val;
                    } else {
                        int b = m >> 11, s = m & (SEQ - 1);
                        int h = n >> 6, d = n & 63;
                        ((_Float16*)outp)[(((size_t)(b * NH + h)) * SEQ + s) * DKK + d] =
                            (_Float16)val;
                    }
                }
            }
        }
    }
}

struct QkvArgs {
    const float *A0, *A1, *A2, *b0, *b1, *b2;
    _Float16 *o0, *o1, *o2;
};

__global__ __launch_bounds__(256) void gemm_qkv(QkvArgs ga, const _Float16* __restrict__ cw) {
    const int z = blockIdx.y;
    const float* A  = (z == 0) ? ga.A0 : (z == 1) ? ga.A1 : ga.A2;
    const float* bi = (z == 0) ? ga.b0 : (z == 1) ? ga.b1 : ga.b2;
    _Float16*    o  = (z == 0) ? ga.o0 : (z == 1) ? ga.o1 : ga.o2;
    gemm_body<0>(A, cw + (size_t)z * D_MODEL * D_MODEL, bi, o,
                 (z == 2) ? 1 : 0, (z == 0) ? QSCALE : 1.0f);
}

__global__ __launch_bounds__(256) void gemm_out(const _Float16* __restrict__ A,
                                                const _Float16* __restrict__ cw,
                                                const float* __restrict__ bias,
                                                float* __restrict__ out) {
    gemm_body<1>(A, cw, bias, out, 2, 1.0f);
}

// ---------------- attention: no K/V staging, no barriers ----------------
// K+V per head = 512KB fp16 -> L2-resident; one tile (16KB) fits L1. Fragments
// loaded straight from global. Only per-wave P goes through LDS (8KB/block).
// Q pre-scaled by 0.125*log2e -> p = exp2(score); masked -> 1.0.
// lsum via all-ones-A MFMA (no VALU adds, no epilogue shuffles).
__global__ __launch_bounds__(256, 4) void attn_fwd(const _Float16* __restrict__ q,
                                                   const _Float16* __restrict__ kk,
                                                   const _Float16* __restrict__ vt,
                                                   const unsigned int* __restrict__ mb,
                                                   _Float16* __restrict__ aout) {
    __shared__ __align__(16) _Float16 plds[4][16 * 64];   // 8192 B total
    const int wg = xswz(blockIdx.x, 1024);
    const int qblk = wg & 31, bh = wg >> 5;
    const int b = bh >> 4, h = bh & 15;
    const int tid = threadIdx.x, wid = tid >> 6, lane = tid & 63;
    const int li = lane & 15, g = lane >> 4;
    const _Float16* qp = q  + (size_t)bh * SEQ * DKK;
    const _Float16* kp = kk + (size_t)bh * SEQ * DKK;
    const _Float16* vp = vt + (size_t)bh * DKK * SEQ;
    const int qrow0 = qblk * 64 + wid * 16;

    half8 qf[2];
#pragma unroll
    for (int s = 0; s < 2; ++s)
        qf[s] = *(const half8*)(qp + (size_t)(qrow0 + li) * DKK + s * 32 + g * 8);

    half8 ones;
#pragma unroll
    for (int j = 0; j < 8; ++j) ones[j] = (_Float16)1.0f;

    f32x4 O[4];
#pragma unroll
    for (int dt = 0; dt < 4; ++dt) O[dt] = fz4();
    f32x4 Ol = fz4();   // ones-column accumulator: every reg = lsum(q=li)

    const unsigned int* m0 = mb + ((size_t)b * SEQ + qrow0 + li) * (SEQ / 32);

    char* pw = (char*)&plds[wid][0];
    const int pswz = (li & 7) << 4;
    const int prow = li * 128;

    // per-lane fragment bases
    const _Float16* kfp = kp + (size_t)li * DKK + g * 8;          // + (kb+t*16)*DKK, +32 for s=1
    const _Float16* vfp = vp + (size_t)li * SEQ + g * 8;          // + dt*16*SEQ + kb, +32 for s=1

    for (int it = 0; it < SEQ / 64; ++it) {
        const int kb = it * 64;
        uint2 ma = *(const uint2*)(m0 + it * 2);

        // S^T = K·Q^T : lane holds P[key=16t+4g+r][q=li]
        f32x4 st[4];
#pragma unroll
        for (int t = 0; t < 4; ++t) st[t] = fz4();
        __builtin_amdgcn_s_setprio(1);
#pragma unroll
        for (int t = 0; t < 4; ++t) {
            const _Float16* kr = kfp + (size_t)(kb + t * 16) * DKK;
            half8 kf0 = *(const half8*)(kr);
            half8 kf1 = *(const half8*)(kr + 32);
            st[t] = __builtin_amdgcn_mfma_f32_16x16x32_f16(kf0, qf[0], st[t], 0, 0, 0);
            st[t] = __builtin_amdgcn_mfma_f32_16x16x32_f16(kf1, qf[1], st[t], 0, 0, 0);
        }
        __builtin_amdgcn_s_setprio(0);

        // issue V-fragment loads now; they fly under the softmax VALU
        half8 vf[4][2];
#pragma unroll
        for (int dt = 0; dt < 4; ++dt) {
            const _Float16* vr = vfp + (size_t)(dt * 16) * SEQ + kb;
            vf[dt][0] = *(const half8*)(vr);
            vf[dt][1] = *(const half8*)(vr + 32);
        }

        // p = exp2(score) [Q pre-scaled]; masked -> 1.0; pack fp16 into P-LDS
#pragma unroll
        for (int t = 0; t < 4; ++t) {
            unsigned wsel = ((t < 2) ? ma.x : ma.y) >> (g * 4);
            const int sh = (t & 1) << 4;
            float e0 = __builtin_amdgcn_exp2f(st[t][0]);
            float e1 = __builtin_amdgcn_exp2f(st[t][1]);
            float e2 = __builtin_amdgcn_exp2f(st[t][2]);
            float e3 = __builtin_amdgcn_exp2f(st[t][3]);
            float p0 = ((wsel >> (sh + 0)) & 1u) ? e0 : 1.0f;
            float p1 = ((wsel >> (sh + 1)) & 1u) ? e1 : 1.0f;
            float p2 = ((wsel >> (sh + 2)) & 1u) ? e2 : 1.0f;
            float p3 = ((wsel >> (sh + 3)) & 1u) ? e3 : 1.0f;
            *(half4*)(pw + prow + ((t * 32 + g * 8) ^ pswz)) = pk4(p0, p1, p2, p3);
        }

        // O^T += V^T·P^T ; lsum via ones-column MFMA (same-wave LDS, lgkmcnt orders)
        half8 pB[2];
#pragma unroll
        for (int s = 0; s < 2; ++s)
            pB[s] = *(const half8*)(pw + prow + ((s * 64 + g * 16) ^ pswz));
        __builtin_amdgcn_s_setprio(1);
        Ol = __builtin_amdgcn_mfma_f32_16x16x32_f16(ones, pB[0], Ol, 0, 0, 0);
        Ol = __builtin_amdgcn_mfma_f32_16x16x32_f16(ones, pB[1], Ol, 0, 0, 0);
#pragma unroll
        for (int dt = 0; dt < 4; ++dt) {
            O[dt] = __builtin_amdgcn_mfma_f32_16x16x32_f16(vf[dt][0], pB[0], O[dt], 0, 0, 0);
            O[dt] = __builtin_amdgcn_mfma_f32_16x16x32_f16(vf[dt][1], pB[1], O[dt], 0, 0, 0);
        }
        __builtin_amdgcn_s_setprio(0);
    }

    // epilogue: every lane already holds lsum(q=li) in Ol[0]
    float inv = 1.0f / Ol[0];
    _Float16* orow = aout + ((size_t)(b * SEQ + qrow0 + li)) * D_MODEL + h * DKK + g * 4;
#pragma unroll
    for (int dt = 0; dt < 4; ++dt)
        *(half4*)(orow + dt * 16) = pk4(O[dt][0] * inv, O[dt][1] * inv,
                                        O[dt][2] * inv, O[dt][3] * inv);
}

extern "C" void kernel_launch(void* const* d_in, const int* in_sizes, int n_in,
                              void* d_out, int out_size, void* d_ws, size_t ws_size,
                              hipStream_t stream) {
    const float* Q    = (const float*)d_in[0];
    const float* Kin  = (const float*)d_in[1];
    const float* Vin  = (const float*)d_in[2];
    const int*   mask = (const int*)d_in[3];
    const float* WQw = (const float*)d_in[4];
    const float* WQb = (const float*)d_in[5];
    const float* WKw = (const float*)d_in[6];
    const float* WKb = (const float*)d_in[7];
    const float* WVw = (const float*)d_in[8];
    const float* WVb = (const float*)d_in[9];
    const float* WOw = (const float*)d_in[10];
    const float* WOb = (const float*)d_in[11];

    char* w = (char*)d_ws;
    const size_t MB = 1ull << 20;
    _Float16* cw  = (_Float16*)(w);                 // [0,8) fp16 weights WQ|WK|WV|WO
    _Float16* ab  = (_Float16*)(w + 8 * MB);        // [8,16) attention out fp16
    _Float16* qb  = (_Float16*)(w + 16 * MB);
    _Float16* kbf = (_Float16*)(w + 24 * MB);
    _Float16* vtb = (_Float16*)(w + 32 * MB);
    unsigned int* mbits = (unsigned int*)(w + 40 * MB);

    conv_w<<<dim3(2048), dim3(256), 0, stream>>>(WQw, WKw, WVw, WOw, cw);
    pack_mask_k<<<dim3(1024), dim3(256), 0, stream>>>(mask, mbits);

    QkvArgs ga;
    ga.A0 = Q;   ga.A1 = Kin; ga.A2 = Vin;
    ga.b0 = WQb; ga.b1 = WKb; ga.b2 = WVb;
    ga.o0 = qb;  ga.o1 = kbf; ga.o2 = vtb;
    gemm_qkv<<<dim3(512, 3), dim3(256), 0, stream>>>(ga, cw);

    attn_fwd<<<dim3(1024), dim3(256), 0, stream>>>(qb, kbf, vtb, mbits, ab);

    gemm_out<<<dim3(512), dim3(256), 0, stream>>>(ab, cw + 3ull * D_MODEL * D_MODEL, WOb,
                                                  (float*)d_out);
}

// Round 8
// 155.092 us; speedup vs baseline: 2.1117x; 2.1117x over previous
//
#include <hip/hip_runtime.h>
#include <stdint.h>

#define D_MODEL 1024
#define NH 16
#define DKK 64
#define SEQ 2048
// softmax scale folded into Q projection: 0.125 * log2(e)
#define QSCALE 0.18033688011112042f

using half8 = __attribute__((ext_vector_type(8))) _Float16;
using half4 = __attribute__((ext_vector_type(4))) _Float16;
using half2v = __attribute__((ext_vector_type(2))) _Float16;
using fp16x2 = __attribute__((ext_vector_type(2))) __fp16;
using f32x4 = __attribute__((ext_vector_type(4))) float;

__device__ __forceinline__ f32x4 fz4() { f32x4 v = {0.f, 0.f, 0.f, 0.f}; return v; }

// async global->LDS, 16B per lane; LDS dest = wave-uniform base + lane*16
__device__ __forceinline__ void gload16(const void* g, void* l) {
    __builtin_amdgcn_global_load_lds(
        (const __attribute__((address_space(1))) unsigned int*)g,
        (__attribute__((address_space(3))) unsigned int*)l, 16, 0, 0);
}

__device__ __forceinline__ half2v pk2(float a, float b) {
    fp16x2 t = __builtin_amdgcn_cvt_pkrtz(a, b);
    return __builtin_bit_cast(half2v, t);
}

__device__ __forceinline__ half4 pk4(float a, float b, float c, float d) {
    half2v lo = pk2(a, b);
    half2v hi = pk2(c, d);
    half4 r; r.x = lo.x; r.y = lo.y; r.z = hi.x; r.w = hi.y;
    return r;
}

// XCD-chunked swizzle
__device__ __forceinline__ int xswz(int bid, int n) {
    return (bid & 7) * (n >> 3) + (bid >> 3);
}

// ---------------- weights fp32 -> fp16: [WQ|WK|WV|WO] ----------------
__global__ __launch_bounds__(256) void conv_w(const float* __restrict__ wq,
                                              const float* __restrict__ wk,
                                              const float* __restrict__ wv,
                                              const float* __restrict__ wo,
                                              _Float16* __restrict__ out) {
    int idx = blockIdx.x * 256 + threadIdx.x;
#pragma unroll
    for (int k = 0; k < 2; ++k) {
        int c = idx + k * 524288;                 // 1,048,576 float4 chunks
        int w = c >> 18;
        const float* src = (w == 0) ? wq : (w == 1) ? wk : (w == 2) ? wv : wo;
        float4 v = ((const float4*)src)[c & 0x3ffff];
        ((half4*)out)[c] = pk4(v.x, v.y, v.z, v.w);
    }
}

// ---------------- mask -> bitmask ----------------
__global__ __launch_bounds__(256) void pack_mask_k(const int* __restrict__ mask,
                                                   unsigned int* __restrict__ mbits) {
    int wid = threadIdx.x >> 6, lane = threadIdx.x & 63;
    int row = blockIdx.x * 4 + wid;
    const int* mrow = mask + (size_t)row * SEQ;
    unsigned int* orow = mbits + (size_t)row * (SEQ / 32);
    for (int it = 0; it < SEQ / 64; ++it) {
        int v = mrow[it * 64 + lane];
        unsigned long long bal = __ballot(v != 0);
        if (lane == 0)       orow[it * 2]     = (unsigned int)(bal & 0xffffffffull);
        else if (lane == 32) orow[it * 2 + 1] = (unsigned int)(bal >> 32);
    }
}

// ---------------- GEMM body (unchanged from round 7) ----------------
template <int AMODE>
__device__ __forceinline__ void gemm_body(const void* __restrict__ Ap,
                                          const _Float16* __restrict__ Wh,
                                          const float* __restrict__ bias,
                                          void* __restrict__ outp, int omode, float scale) {
    __shared__ __align__(16) _Float16 Asm[2][64 * 64];
    __shared__ __align__(16) _Float16 Bsm[2][128 * 64];
    const int tid = threadIdx.x;
    const int wg = xswz(blockIdx.x, 512);
    const int bm = wg >> 3, bn = wg & 7;
    const int wid = tid >> 6, lane = tid & 63;
    const int li = lane & 15, g = lane >> 4;
    const int wm = wid >> 1, wn = wid & 1;

    const int brow = wid * 32 + (lane >> 3);
    const char* bsrc = (const char*)(Wh + (size_t)(bn * 128 + brow) * D_MODEL)
                       + (((lane & 7) ^ (brow & 7)) * 16);
    const int bdst = wid * 32 * 128;

    const int arow0 = wid * 16 + (lane >> 2);
    const float* asrc4 = (const float*)Ap + (size_t)(bm * 64 + arow0) * D_MODEL + (lane & 3) * 16;
    const int awo0 = arow0 * 128 + (((lane & 3) * 32)      ^ ((arow0 & 7) << 4));
    const int awo1 = arow0 * 128 + (((lane & 3) * 32 + 16) ^ ((arow0 & 7) << 4));
    const int arow1 = wid * 16 + (lane >> 3);
    const char* asrc1 = (const char*)Ap + (size_t)(bm * 64 + arow1) * (D_MODEL * 2)
                        + (((lane & 7) ^ (arow1 & 7)) * 16);
    const int adst1 = wid * 16 * 128;

    f32x4 acc[2][4];
#pragma unroll
    for (int i = 0; i < 2; ++i)
#pragma unroll
        for (int j = 0; j < 4; ++j) acc[i][j] = fz4();

    const int o0 = ((g << 4))      ^ ((li & 7) << 4);
    const int o1 = (64 + (g << 4)) ^ ((li & 7) << 4);
    const int abase = wm * 4096 + li * 128;
    const int bbase = wn * 8192 + li * 128;

    auto stage = [&](int it, int buf) {
        const char* bs = bsrc + it * 128;
        char* bd = (char*)&Bsm[buf][0] + bdst;
        gload16(bs,             bd);
        gload16(bs +  8 * 2048, bd + 1024);
        gload16(bs + 16 * 2048, bd + 2048);
        gload16(bs + 24 * 2048, bd + 3072);
        if constexpr (AMODE == 0) {
            const float* s = asrc4 + it * 64;
            float4 v0 = *(const float4*)(s);
            float4 v1 = *(const float4*)(s + 4);
            float4 v2 = *(const float4*)(s + 8);
            float4 v3 = *(const float4*)(s + 12);
            char* d = (char*)&Asm[buf][0];
            half8 h0, h1;
            *(half4*)&h0 = pk4(v0.x, v0.y, v0.z, v0.w);
            *((half4*)&h0 + 1) = pk4(v1.x, v1.y, v1.z, v1.w);
            *(half4*)&h1 = pk4(v2.x, v2.y, v2.z, v2.w);
            *((half4*)&h1 + 1) = pk4(v3.x, v3.y, v3.z, v3.w);
            *(half8*)(d + awo0) = h0;
            *(half8*)(d + awo1) = h1;
        } else {
            const char* as = asrc1 + it * 128;
            char* ad = (char*)&Asm[buf][0] + adst1;
            gload16(as,            ad);
            gload16(as + 8 * 2048, ad + 1024);
        }
    };

    stage(0, 0);
    __syncthreads();

    for (int it = 0; it < 16; ++it) {
        const int cur = it & 1;
        if (it + 1 < 16) stage(it + 1, cur ^ 1);
        const char* ab = (const char*)&Asm[cur][0];
        const char* bb = (const char*)&Bsm[cur][0];
#pragma unroll
        for (int s = 0; s < 2; ++s) {
            const int oS = s ? o1 : o0;
            half8 af0 = *(const half8*)(ab + abase + 0    + oS);
            half8 af1 = *(const half8*)(ab + abase + 2048 + oS);
            half8 bf[4];
#pragma unroll
            for (int nt = 0; nt < 4; ++nt)
                bf[nt] = *(const half8*)(bb + bbase + nt * 2048 + oS);
#pragma unroll
            for (int nt = 0; nt < 4; ++nt) {
                acc[0][nt] = __builtin_amdgcn_mfma_f32_16x16x32_f16(af0, bf[nt], acc[0][nt], 0, 0, 0);
                acc[1][nt] = __builtin_amdgcn_mfma_f32_16x16x32_f16(af1, bf[nt], acc[1][nt], 0, 0, 0);
            }
        }
        __syncthreads();
    }

#pragma unroll
    for (int nt = 0; nt < 4; ++nt) {
        int n = bn * 128 + wn * 64 + nt * 16 + li;
        float bv = bias[n];
#pragma unroll
        for (int mt = 0; mt < 2; ++mt) {
            if (omode == 1) {
                int s0 = bm * 64 + wm * 32 + mt * 16 + g * 4;
                int b = (bm * 64) >> 11;
                int h = n >> 6, d = n & 63;
                half4 hv = pk4(acc[mt][nt][0] + bv, acc[mt][nt][1] + bv,
                               acc[mt][nt][2] + bv, acc[mt][nt][3] + bv);
                *(half4*)((_Float16*)outp +
                          ((((size_t)(b * NH + h)) * DKK + d) * SEQ + (s0 & (SEQ - 1)))) = hv;
            } else {
#pragma unroll
                for (int r = 0; r < 4; ++r) {
                    int m = bm * 64 + wm * 32 + mt * 16 + g * 4 + r;
                    float val = (acc[mt][nt][r] + bv) * scale;
                    if (omode == 2) {
                        ((float*)outp)[(size_t)m * D_MODEL + n] = val;
                    } else {
                        int b = m >> 11, s = m & (SEQ - 1);
                        int h = n >> 6, d = n & 63;
                        ((_Float16*)outp)[(((size_t)(b * NH + h)) * SEQ + s) * DKK + d] =
                            (_Float16)val;
                    }
                }
            }
        }
    }
}

struct QkvArgs {
    const float *A0, *A1, *A2, *b0, *b1, *b2;
    _Float16 *o0, *o1, *o2;
};

__global__ __launch_bounds__(256) void gemm_qkv(QkvArgs ga, const _Float16* __restrict__ cw) {
    const int z = blockIdx.y;
    const float* A  = (z == 0) ? ga.A0 : (z == 1) ? ga.A1 : ga.A2;
    const float* bi = (z == 0) ? ga.b0 : (z == 1) ? ga.b1 : ga.b2;
    _Float16*    o  = (z == 0) ? ga.o0 : (z == 1) ? ga.o1 : ga.o2;
    gemm_body<0>(A, cw + (size_t)z * D_MODEL * D_MODEL, bi, o,
                 (z == 2) ? 1 : 0, (z == 0) ? QSCALE : 1.0f);
}

__global__ __launch_bounds__(256) void gemm_out(const _Float16* __restrict__ A,
                                                const _Float16* __restrict__ cw,
                                                const float* __restrict__ bias,
                                                float* __restrict__ out) {
    gemm_body<1>(A, cw, bias, out, 2, 1.0f);
}

// ---------------- attention: KVBLK=32 staged, LDS 20480B -> ~8 blocks/CU ----------------
// 4 waves x 16 q-rows (QBLK=64). K/V double-buffered via global_load_lds.
// Q pre-scaled by 0.125*log2e -> p = exp2(score); masked -> 1.0.
// lsum via all-ones-A MFMA. P per-wave LDS, 64B pitch, (li&3) XOR.
__global__ __launch_bounds__(256, 8) void attn_fwd(const _Float16* __restrict__ q,
                                                   const _Float16* __restrict__ kk,
                                                   const _Float16* __restrict__ vt,
                                                   const unsigned int* __restrict__ mb,
                                                   _Float16* __restrict__ aout) {
    __shared__ __align__(16) _Float16 klds[2][32 * 64];   // [key][d] 128B rows, 8192 B
    __shared__ __align__(16) _Float16 vlds[2][64 * 32];   // [d][key] 64B rows,  8192 B
    __shared__ __align__(16) _Float16 plds[4][16 * 32];   // per-wave P, 64B pitch, 4096 B
    const int wg = xswz(blockIdx.x, 1024);
    const int qblk = wg & 31, bh = wg >> 5;
    const int b = bh >> 4, h = bh & 15;
    const int tid = threadIdx.x, wid = tid >> 6, lane = tid & 63;
    const int li = lane & 15, g = lane >> 4;
    const _Float16* qp = q  + (size_t)bh * SEQ * DKK;
    const _Float16* kp = kk + (size_t)bh * SEQ * DKK;
    const _Float16* vp = vt + (size_t)bh * DKK * SEQ;
    const int qrow0 = qblk * 64 + wid * 16;

    half8 qf[2];
#pragma unroll
    for (int s = 0; s < 2; ++s)
        qf[s] = *(const half8*)(qp + (size_t)(qrow0 + li) * DKK + s * 32 + g * 8);

    half8 ones;
#pragma unroll
    for (int j = 0; j < 8; ++j) ones[j] = (_Float16)1.0f;

    // K staging: wave wid stages rows wid*8 + (lane>>3), chunk (lane&7) of 128B row
    const int srowK = wid * 8 + (lane >> 3);
    const char* ksrc = (const char*)(kp + (size_t)srowK * DKK)
                       + (((lane & 7) ^ (srowK & 7)) * 16);
    const int kdst = wid * 1024;
    // V staging: wave wid stages rows wid*16 + (lane>>2), chunk (lane&3) of 64B row
    const int srowV = wid * 16 + (lane >> 2);
    const char* vsrc = (const char*)(vp + (size_t)srowV * SEQ)
                       + (((lane & 3) ^ (srowV & 3)) * 16);
    const int vdst = wid * 1024;

    auto stage = [&](int it, int buf) {
        gload16(ksrc + (size_t)it * 4096, (char*)&klds[buf][0] + kdst);
        gload16(vsrc + (size_t)it * 64,   (char*)&vlds[buf][0] + vdst);
    };

    f32x4 O[4];
#pragma unroll
    for (int dt = 0; dt < 4; ++dt) O[dt] = fz4();
    f32x4 Ol = fz4();   // ones-column accumulator: every reg = lsum(q=li)

    const unsigned int* m0 = mb + ((size_t)b * SEQ + qrow0 + li) * (SEQ / 32);

    char* pw = (char*)&plds[wid][0];
    const int pxor = (li & 3) << 4;
    const int pwo = li * 64;                        // + ((t*32+g*8) ^ pxor)
    const int pro = li * 64 + ((g * 16) ^ pxor);

    const int o0 = ((g << 4))      ^ ((li & 7) << 4);
    const int o1 = (64 + (g << 4)) ^ ((li & 7) << 4);
    const int kfb = li * 128;                       // K frag: + t*2048 + o0/o1
    const int vfb = li * 64 + ((g << 4) ^ ((li & 3) << 4));   // V frag: + dt*1024

    stage(0, 0);
    __syncthreads();

    for (int it = 0; it < SEQ / 32; ++it) {
        const int cur = it & 1;
        if (it + 1 < SEQ / 32) stage(it + 1, cur ^ 1);
        unsigned ma = m0[it];

        // S^T = K·Q^T : lane holds P[key=16t+4g+r][q=li], t=0..1
        f32x4 st[2];
        st[0] = fz4(); st[1] = fz4();
        const char* kb_ = (const char*)&klds[cur][0];
        __builtin_amdgcn_s_setprio(1);
#pragma unroll
        for (int t = 0; t < 2; ++t) {
            half8 kf0 = *(const half8*)(kb_ + kfb + t * 2048 + o0);
            half8 kf1 = *(const half8*)(kb_ + kfb + t * 2048 + o1);
            st[t] = __builtin_amdgcn_mfma_f32_16x16x32_f16(kf0, qf[0], st[t], 0, 0, 0);
            st[t] = __builtin_amdgcn_mfma_f32_16x16x32_f16(kf1, qf[1], st[t], 0, 0, 0);
        }
        __builtin_amdgcn_s_setprio(0);

        // p = exp2(score) [Q pre-scaled]; masked -> 1.0; pack fp16 into P-LDS
#pragma unroll
        for (int t = 0; t < 2; ++t) {
            unsigned wsel = ma >> (t * 16 + g * 4);
            float e0 = __builtin_amdgcn_exp2f(st[t][0]);
            float e1 = __builtin_amdgcn_exp2f(st[t][1]);
            float e2 = __builtin_amdgcn_exp2f(st[t][2]);
            float e3 = __builtin_amdgcn_exp2f(st[t][3]);
            float p0 = ((wsel >> 0) & 1u) ? e0 : 1.0f;
            float p1 = ((wsel >> 1) & 1u) ? e1 : 1.0f;
            float p2 = ((wsel >> 2) & 1u) ? e2 : 1.0f;
            float p3 = ((wsel >> 3) & 1u) ? e3 : 1.0f;
            *(half4*)(pw + pwo + ((t * 32 + g * 8) ^ pxor)) = pk4(p0, p1, p2, p3);
        }

        // O^T += V^T·P^T ; lsum via ones-column MFMA (same-wave LDS, lgkmcnt orders)
        half8 pB = *(const half8*)(pw + pro);
        const char* vb_ = (const char*)&vlds[cur][0];
        __builtin_amdgcn_s_setprio(1);
        Ol = __builtin_amdgcn_mfma_f32_16x16x32_f16(ones, pB, Ol, 0, 0, 0);
#pragma unroll
        for (int dt = 0; dt < 4; ++dt) {
            half8 vf = *(const half8*)(vb_ + vfb + dt * 1024);
            O[dt] = __builtin_amdgcn_mfma_f32_16x16x32_f16(vf, pB, O[dt], 0, 0, 0);
        }
        __builtin_amdgcn_s_setprio(0);
        __syncthreads();
    }

    // epilogue: every lane already holds lsum(q=li) in Ol[0]
    float inv = 1.0f / Ol[0];
    _Float16* orow = aout + ((size_t)(b * SEQ + qrow0 + li)) * D_MODEL + h * DKK + g * 4;
#pragma unroll
    for (int dt = 0; dt < 4; ++dt)
        *(half4*)(orow + dt * 16) = pk4(O[dt][0] * inv, O[dt][1] * inv,
                                        O[dt][2] * inv, O[dt][3] * inv);
}

extern "C" void kernel_launch(void* const* d_in, const int* in_sizes, int n_in,
                              void* d_out, int out_size, void* d_ws, size_t ws_size,
                              hipStream_t stream) {
    const float* Q    = (const float*)d_in[0];
    const float* Kin  = (const float*)d_in[1];
    const float* Vin  = (const float*)d_in[2];
    const int*   mask = (const int*)d_in[3];
    const float* WQw = (const float*)d_in[4];
    const float* WQb = (const float*)d_in[5];
    const float* WKw = (const float*)d_in[6];
    const float* WKb = (const float*)d_in[7];
    const float* WVw = (const float*)d_in[8];
    const float* WVb = (const float*)d_in[9];
    const float* WOw = (const float*)d_in[10];
    const float* WOb = (const float*)d_in[11];

    char* w = (char*)d_ws;
    const size_t MB = 1ull << 20;
    _Float16* cw  = (_Float16*)(w);                 // [0,8) fp16 weights WQ|WK|WV|WO
    _Float16* ab  = (_Float16*)(w + 8 * MB);        // [8,16) attention out fp16
    _Float16* qb  = (_Float16*)(w + 16 * MB);
    _Float16* kbf = (_Float16*)(w + 24 * MB);
    _Float16* vtb = (_Float16*)(w + 32 * MB);
    unsigned int* mbits = (unsigned int*)(w + 40 * MB);

    conv_w<<<dim3(2048), dim3(256), 0, stream>>>(WQw, WKw, WVw, WOw, cw);
    pack_mask_k<<<dim3(1024), dim3(256), 0, stream>>>(mask, mbits);

    QkvArgs ga;
    ga.A0 = Q;   ga.A1 = Kin; ga.A2 = Vin;
    ga.b0 = WQb; ga.b1 = WKb; ga.b2 = WVb;
    ga.o0 = qb;  ga.o1 = kbf; ga.o2 = vtb;
    gemm_qkv<<<dim3(512, 3), dim3(256), 0, stream>>>(ga, cw);

    attn_fwd<<<dim3(1024), dim3(256), 0, stream>>>(qb, kbf, vtb, mbits, ab);

    gemm_out<<<dim3(512), dim3(256), 0, stream>>>(ab, cw + 3ull * D_MODEL * D_MODEL, WOb,
                                                  (float*)d_out);
}

// Round 9
// 152.085 us; speedup vs baseline: 2.1534x; 1.0198x over previous
//
#include <hip/hip_runtime.h>
#include <stdint.h>

#define D_MODEL 1024
#define NH 16
#define DKK 64
#define SEQ 2048
// softmax scale folded into Q projection: 0.125 * log2(e)
#define QSCALE 0.18033688011112042f

using half8 = __attribute__((ext_vector_type(8))) _Float16;
using half4 = __attribute__((ext_vector_type(4))) _Float16;
using half2v = __attribute__((ext_vector_type(2))) _Float16;
using fp16x2 = __attribute__((ext_vector_type(2))) __fp16;
using f32x4 = __attribute__((ext_vector_type(4))) float;
using f32x16 = __attribute__((ext_vector_type(16))) float;

__device__ __forceinline__ f32x4 fz4() { f32x4 v = {0.f, 0.f, 0.f, 0.f}; return v; }

// async global->LDS, 16B per lane; LDS dest = wave-uniform base + lane*16
__device__ __forceinline__ void gload16(const void* g, void* l) {
    __builtin_amdgcn_global_load_lds(
        (const __attribute__((address_space(1))) unsigned int*)g,
        (__attribute__((address_space(3))) unsigned int*)l, 16, 0, 0);
}

__device__ __forceinline__ half2v pk2(float a, float b) {
    fp16x2 t = __builtin_amdgcn_cvt_pkrtz(a, b);
    return __builtin_bit_cast(half2v, t);
}

__device__ __forceinline__ half4 pk4(float a, float b, float c, float d) {
    half2v lo = pk2(a, b);
    half2v hi = pk2(c, d);
    half4 r; r.x = lo.x; r.y = lo.y; r.z = hi.x; r.w = hi.y;
    return r;
}

// XCD-chunked swizzle
__device__ __forceinline__ int xswz(int bid, int n) {
    return (bid & 7) * (n >> 3) + (bid >> 3);
}

// ---------------- weights fp32 -> fp16: [WQ|WK|WV|WO] ----------------
__global__ __launch_bounds__(256) void conv_w(const float* __restrict__ wq,
                                              const float* __restrict__ wk,
                                              const float* __restrict__ wv,
                                              const float* __restrict__ wo,
                                              _Float16* __restrict__ out) {
    int idx = blockIdx.x * 256 + threadIdx.x;
#pragma unroll
    for (int k = 0; k < 2; ++k) {
        int c = idx + k * 524288;                 // 1,048,576 float4 chunks
        int w = c >> 18;
        const float* src = (w == 0) ? wq : (w == 1) ? wk : (w == 2) ? wv : wo;
        float4 v = ((const float4*)src)[c & 0x3ffff];
        ((half4*)out)[c] = pk4(v.x, v.y, v.z, v.w);
    }
}

// ---------------- mask -> bitmask ----------------
__global__ __launch_bounds__(256) void pack_mask_k(const int* __restrict__ mask,
                                                   unsigned int* __restrict__ mbits) {
    int wid = threadIdx.x >> 6, lane = threadIdx.x & 63;
    int row = blockIdx.x * 4 + wid;
    const int* mrow = mask + (size_t)row * SEQ;
    unsigned int* orow = mbits + (size_t)row * (SEQ / 32);
    for (int it = 0; it < SEQ / 64; ++it) {
        int v = mrow[it * 64 + lane];
        unsigned long long bal = __ballot(v != 0);
        if (lane == 0)       orow[it * 2]     = (unsigned int)(bal & 0xffffffffull);
        else if (lane == 32) orow[it * 2 + 1] = (unsigned int)(bal >> 32);
    }
}

// ---------------- GEMM body (unchanged) ----------------
template <int AMODE>
__device__ __forceinline__ void gemm_body(const void* __restrict__ Ap,
                                          const _Float16* __restrict__ Wh,
                                          const float* __restrict__ bias,
                                          void* __restrict__ outp, int omode, float scale) {
    __shared__ __align__(16) _Float16 Asm[2][64 * 64];
    __shared__ __align__(16) _Float16 Bsm[2][128 * 64];
    const int tid = threadIdx.x;
    const int wg = xswz(blockIdx.x, 512);
    const int bm = wg >> 3, bn = wg & 7;
    const int wid = tid >> 6, lane = tid & 63;
    const int li = lane & 15, g = lane >> 4;
    const int wm = wid >> 1, wn = wid & 1;

    const int brow = wid * 32 + (lane >> 3);
    const char* bsrc = (const char*)(Wh + (size_t)(bn * 128 + brow) * D_MODEL)
                       + (((lane & 7) ^ (brow & 7)) * 16);
    const int bdst = wid * 32 * 128;

    const int arow0 = wid * 16 + (lane >> 2);
    const float* asrc4 = (const float*)Ap + (size_t)(bm * 64 + arow0) * D_MODEL + (lane & 3) * 16;
    const int awo0 = arow0 * 128 + (((lane & 3) * 32)      ^ ((arow0 & 7) << 4));
    const int awo1 = arow0 * 128 + (((lane & 3) * 32 + 16) ^ ((arow0 & 7) << 4));
    const int arow1 = wid * 16 + (lane >> 3);
    const char* asrc1 = (const char*)Ap + (size_t)(bm * 64 + arow1) * (D_MODEL * 2)
                        + (((lane & 7) ^ (arow1 & 7)) * 16);
    const int adst1 = wid * 16 * 128;

    f32x4 acc[2][4];
#pragma unroll
    for (int i = 0; i < 2; ++i)
#pragma unroll
        for (int j = 0; j < 4; ++j) acc[i][j] = fz4();

    const int o0 = ((g << 4))      ^ ((li & 7) << 4);
    const int o1 = (64 + (g << 4)) ^ ((li & 7) << 4);
    const int abase = wm * 4096 + li * 128;
    const int bbase = wn * 8192 + li * 128;

    auto stage = [&](int it, int buf) {
        const char* bs = bsrc + it * 128;
        char* bd = (char*)&Bsm[buf][0] + bdst;
        gload16(bs,             bd);
        gload16(bs +  8 * 2048, bd + 1024);
        gload16(bs + 16 * 2048, bd + 2048);
        gload16(bs + 24 * 2048, bd + 3072);
        if constexpr (AMODE == 0) {
            const float* s = asrc4 + it * 64;
            float4 v0 = *(const float4*)(s);
            float4 v1 = *(const float4*)(s + 4);
            float4 v2 = *(const float4*)(s + 8);
            float4 v3 = *(const float4*)(s + 12);
            char* d = (char*)&Asm[buf][0];
            half8 h0, h1;
            *(half4*)&h0 = pk4(v0.x, v0.y, v0.z, v0.w);
            *((half4*)&h0 + 1) = pk4(v1.x, v1.y, v1.z, v1.w);
            *(half4*)&h1 = pk4(v2.x, v2.y, v2.z, v2.w);
            *((half4*)&h1 + 1) = pk4(v3.x, v3.y, v3.z, v3.w);
            *(half8*)(d + awo0) = h0;
            *(half8*)(d + awo1) = h1;
        } else {
            const char* as = asrc1 + it * 128;
            char* ad = (char*)&Asm[buf][0] + adst1;
            gload16(as,            ad);
            gload16(as + 8 * 2048, ad + 1024);
        }
    };

    stage(0, 0);
    __syncthreads();

    for (int it = 0; it < 16; ++it) {
        const int cur = it & 1;
        if (it + 1 < 16) stage(it + 1, cur ^ 1);
        const char* ab = (const char*)&Asm[cur][0];
        const char* bb = (const char*)&Bsm[cur][0];
#pragma unroll
        for (int s = 0; s < 2; ++s) {
            const int oS = s ? o1 : o0;
            half8 af0 = *(const half8*)(ab + abase + 0    + oS);
            half8 af1 = *(const half8*)(ab + abase + 2048 + oS);
            half8 bf[4];
#pragma unroll
            for (int nt = 0; nt < 4; ++nt)
                bf[nt] = *(const half8*)(bb + bbase + nt * 2048 + oS);
#pragma unroll
            for (int nt = 0; nt < 4; ++nt) {
                acc[0][nt] = __builtin_amdgcn_mfma_f32_16x16x32_f16(af0, bf[nt], acc[0][nt], 0, 0, 0);
                acc[1][nt] = __builtin_amdgcn_mfma_f32_16x16x32_f16(af1, bf[nt], acc[1][nt], 0, 0, 0);
            }
        }
        __syncthreads();
    }

#pragma unroll
    for (int nt = 0; nt < 4; ++nt) {
        int n = bn * 128 + wn * 64 + nt * 16 + li;
        float bv = bias[n];
#pragma unroll
        for (int mt = 0; mt < 2; ++mt) {
            if (omode == 1) {
                int s0 = bm * 64 + wm * 32 + mt * 16 + g * 4;
                int b = (bm * 64) >> 11;
                int h = n >> 6, d = n & 63;
                half4 hv = pk4(acc[mt][nt][0] + bv, acc[mt][nt][1] + bv,
                               acc[mt][nt][2] + bv, acc[mt][nt][3] + bv);
                *(half4*)((_Float16*)outp +
                          ((((size_t)(b * NH + h)) * DKK + d) * SEQ + (s0 & (SEQ - 1)))) = hv;
            } else {
#pragma unroll
                for (int r = 0; r < 4; ++r) {
                    int m = bm * 64 + wm * 32 + mt * 16 + g * 4 + r;
                    float val = (acc[mt][nt][r] + bv) * scale;
                    if (omode == 2) {
                        ((float*)outp)[(size_t)m * D_MODEL + n] = val;
                    } else {
                        int b = m >> 11, s = m & (SEQ - 1);
                        int h = n >> 6, d = n & 63;
                        ((_Float16*)outp)[(((size_t)(b * NH + h)) * SEQ + s) * DKK + d] =
                            (_Float16)val;
                    }
                }
            }
        }
    }
}

struct QkvArgs {
    const float *A0, *A1, *A2, *b0, *b1, *b2;
    _Float16 *o0, *o1, *o2;
};

__global__ __launch_bounds__(256) void gemm_qkv(QkvArgs ga, const _Float16* __restrict__ cw) {
    const int z = blockIdx.y;
    const float* A  = (z == 0) ? ga.A0 : (z == 1) ? ga.A1 : ga.A2;
    const float* bi = (z == 0) ? ga.b0 : (z == 1) ? ga.b1 : ga.b2;
    _Float16*    o  = (z == 0) ? ga.o0 : (z == 1) ? ga.o1 : ga.o2;
    gemm_body<0>(A, cw + (size_t)z * D_MODEL * D_MODEL, bi, o,
                 (z == 2) ? 1 : 0, (z == 0) ? QSCALE : 1.0f);
}

__global__ __launch_bounds__(256) void gemm_out(const _Float16* __restrict__ A,
                                                const _Float16* __restrict__ cw,
                                                const float* __restrict__ bias,
                                                float* __restrict__ out) {
    gemm_body<1>(A, cw, bias, out, 2, 1.0f);
}

// ---------------- attention: 32x32 MFMA, in-register P, no P-LDS ----------------
// Block = 64 q-rows x full KV. 4 waves = (q-half) x (key-half) of each staged
// 64x64 tile; each wave: 32q x 32keys via mfma_32x32x16. Fixed-max softmax makes
// the key-split additive -> one LDS O-combine in the epilogue. P^T rebuilt in
// registers from C-layout via cvt_pk + shfl_xor(32) (two lane-halves only).
// K/V staging identical to round 6 (dbuf, gload16, XOR-swizzled 128B rows).
__global__ __launch_bounds__(256, 4) void attn_fwd(const _Float16* __restrict__ q,
                                                   const _Float16* __restrict__ kk,
                                                   const _Float16* __restrict__ vt,
                                                   const unsigned int* __restrict__ mb,
                                                   _Float16* __restrict__ aout) {
    __shared__ __align__(16) char smem[32768];
    // klds(buf) = smem + buf*8192        : [64 keys][64 d], 128B rows, pre-swizzled
    // vlds(buf) = smem + 16384 + buf*8192: [64 d][64 keys], 128B rows, pre-swizzled
    const int wg = xswz(blockIdx.x, 1024);
    const int qblk = wg & 31, bh = wg >> 5;
    const int b = bh >> 4, h = bh & 15;
    const int tid = threadIdx.x, wid = tid >> 6, lane = tid & 63;
    const int l31 = lane & 31, hi = lane >> 5;
    const int qh = wid & 1, kh = wid >> 1;     // wave -> (q-half, key-half)
    const _Float16* qp = q  + (size_t)bh * SEQ * DKK;
    const _Float16* kp = kk + (size_t)bh * SEQ * DKK;
    const _Float16* vp = vt + (size_t)bh * DKK * SEQ;
    const int qrow = qblk * 64 + qh * 32 + l31;

    // Q as B-operand: lane holds Q[qrow][s*16 + hi*8 + 0..7]
    half8 qf[4];
#pragma unroll
    for (int s = 0; s < 4; ++s)
        qf[s] = *(const half8*)(qp + (size_t)qrow * DKK + s * 16 + hi * 8);

    // staging (r6 pattern): wave wid stages rows wid*16 + {0..7, 8..15}
    const int srow = wid * 16 + (lane >> 3);
    const int sswz = ((lane & 7) ^ (srow & 7)) * 16;
    const char* ksrc = (const char*)(kp + (size_t)srow * DKK) + sswz;
    const char* vsrc = (const char*)(vp + (size_t)srow * SEQ) + sswz;
    const int sdst = wid * 2048;

    auto stage = [&](int it, int buf) {
        const char* ks = ksrc + (size_t)it * 8192;
        const char* vs = vsrc + (size_t)it * 128;
        char* kd = smem + buf * 8192 + sdst;
        char* vd = smem + 16384 + buf * 8192 + sdst;
        gload16(ks,                       kd);
        gload16(ks + 8 * 128,             kd + 1024);
        gload16(vs,                       vd);
        gload16(vs + 8 * (size_t)SEQ * 2, vd + 1024);
    };

    f32x16 O0, O1;
#pragma unroll
    for (int j = 0; j < 16; ++j) { O0[j] = 0.f; O1[j] = 0.f; }
    float lsum = 0.f;

    const unsigned int* mrow = mb + (size_t)(b * SEQ + qrow) * (SEQ / 32);

    // LDS fragment-read bases (row*128 + ((chunk ^ (row&7))<<4))
    const int krow = kh * 32 + l31;
    const int kbase = krow * 128;
    const int krx = (krow & 7);
    const int v0row = l31;            // dt=0
    const int v1row = 32 + l31;       // dt=1

    stage(0, 0);
    __syncthreads();

    for (int it = 0; it < SEQ / 64; ++it) {
        const int cur = it & 1;
        if (it + 1 < SEQ / 64) stage(it + 1, cur ^ 1);
        const unsigned mw = mrow[it * 2 + kh] >> (hi * 4);

        // S^T = K·Q^T : C col = q (l31), row = key = (reg&3)+8*(reg>>2)+4*hi
        f32x16 st;
#pragma unroll
        for (int j = 0; j < 16; ++j) st[j] = 0.f;
        const char* kb_ = smem + cur * 8192;
        __builtin_amdgcn_s_setprio(1);
#pragma unroll
        for (int s = 0; s < 4; ++s) {
            const int c = s * 2 + hi;
            half8 kf = *(const half8*)(kb_ + kbase + ((c ^ krx) << 4));
            st = __builtin_amdgcn_mfma_f32_32x32x16_f16(kf, qf[s], st, 0, 0, 0);
        }
        __builtin_amdgcn_s_setprio(0);

        // softmax (fixed max 0) + mask + pack to fp16 words
        unsigned w[8];
#pragma unroll
        for (int rq = 0; rq < 4; ++rq) {
            float e0 = __builtin_amdgcn_exp2f(st[rq * 4 + 0]);
            float e1 = __builtin_amdgcn_exp2f(st[rq * 4 + 1]);
            float e2 = __builtin_amdgcn_exp2f(st[rq * 4 + 2]);
            float e3 = __builtin_amdgcn_exp2f(st[rq * 4 + 3]);
            float p0 = ((mw >> (8 * rq + 0)) & 1u) ? e0 : 1.0f;
            float p1 = ((mw >> (8 * rq + 1)) & 1u) ? e1 : 1.0f;
            float p2 = ((mw >> (8 * rq + 2)) & 1u) ? e2 : 1.0f;
            float p3 = ((mw >> (8 * rq + 3)) & 1u) ? e3 : 1.0f;
            lsum += (p0 + p1) + (p2 + p3);
            w[2 * rq]     = __builtin_bit_cast(unsigned, pk2(p0, p1));
            w[2 * rq + 1] = __builtin_bit_cast(unsigned, pk2(p2, p3));
        }

        // rebuild P^T B-fragments in registers: one half-exchange per word pair
        half8 pfrag[2];
#pragma unroll
        for (int s2 = 0; s2 < 2; ++s2) {
            unsigned a0 = w[s2 * 4 + 0], a1 = w[s2 * 4 + 1];
            unsigned a2 = w[s2 * 4 + 2], a3 = w[s2 * 4 + 3];
            unsigned t0 = (unsigned)__shfl_xor((int)(hi ? a0 : a2), 32);
            unsigned t1 = (unsigned)__shfl_xor((int)(hi ? a1 : a3), 32);
            uint4 f;
            f.x = hi ? t0 : a0;
            f.y = hi ? t1 : a1;
            f.z = hi ? a2 : t0;
            f.w = hi ? a3 : t1;
            pfrag[s2] = __builtin_bit_cast(half8, f);
        }

        // O^T += V^T·P^T
        const char* vb_ = smem + 16384 + cur * 8192;
        __builtin_amdgcn_s_setprio(1);
#pragma unroll
        for (int s2 = 0; s2 < 2; ++s2) {
            const int c = kh * 4 + s2 * 2 + hi;
            half8 vf0 = *(const half8*)(vb_ + v0row * 128 + ((c ^ (v0row & 7)) << 4));
            half8 vf1 = *(const half8*)(vb_ + v1row * 128 + ((c ^ (v1row & 7)) << 4));
            O0 = __builtin_amdgcn_mfma_f32_32x32x16_f16(vf0, pfrag[s2], O0, 0, 0, 0);
            O1 = __builtin_amdgcn_mfma_f32_32x32x16_f16(vf1, pfrag[s2], O1, 0, 0, 0);
        }
        __builtin_amdgcn_s_setprio(0);
        __syncthreads();
    }

    // ---- epilogue: combine key-halves (waves w and w+2 share q-rows) ----
    lsum += __shfl_xor(lsum, 32);      // complete this wave's 32-key lsum per q

    const int SSTR = 36;               // f32 per lane slot (144B, 16B-aligned, bank-spread)
    float* scr = (float*)smem;
    float* lscr = (float*)(smem + 2 * 64 * SSTR * 4);   // 18432
    if (kh == 1) {
        float* dst = scr + (size_t)qh * (64 * SSTR) + lane * SSTR;
#pragma unroll
        for (int j = 0; j < 4; ++j) {
            *(f32x4*)(dst + j * 4)      = *((f32x4*)&O0 + j);
            *(f32x4*)(dst + 16 + j * 4) = *((f32x4*)&O1 + j);
        }
        if (hi == 0) lscr[qh * 32 + l31] = lsum;
    }
    __syncthreads();
    if (kh == 0) {
        const float* src = scr + (size_t)qh * (64 * SSTR) + lane * SSTR;
#pragma unroll
        for (int j = 0; j < 16; ++j) { O0[j] += src[j]; O1[j] += src[16 + j]; }
        float inv = 1.0f / (lsum + lscr[qh * 32 + l31]);
        _Float16* orow = aout + ((size_t)(b * SEQ + qrow)) * D_MODEL + h * DKK + hi * 4;
#pragma unroll
        for (int rq = 0; rq < 4; ++rq) {
            *(half4*)(orow + 8 * rq) =
                pk4(O0[rq * 4 + 0] * inv, O0[rq * 4 + 1] * inv,
                    O0[rq * 4 + 2] * inv, O0[rq * 4 + 3] * inv);
            *(half4*)(orow + 32 + 8 * rq) =
                pk4(O1[rq * 4 + 0] * inv, O1[rq * 4 + 1] * inv,
                    O1[rq * 4 + 2] * inv, O1[rq * 4 + 3] * inv);
        }
    }
}

extern "C" void kernel_launch(void* const* d_in, const int* in_sizes, int n_in,
                              void* d_out, int out_size, void* d_ws, size_t ws_size,
                              hipStream_t stream) {
    const float* Q    = (const float*)d_in[0];
    const float* Kin  = (const float*)d_in[1];
    const float* Vin  = (const float*)d_in[2];
    const int*   mask = (const int*)d_in[3];
    const float* WQw = (const float*)d_in[4];
    const float* WQb = (const float*)d_in[5];
    const float* WKw = (const float*)d_in[6];
    const float* WKb = (const float*)d_in[7];
    const float* WVw = (const float*)d_in[8];
    const float* WVb = (const float*)d_in[9];
    const float* WOw = (const float*)d_in[10];
    const float* WOb = (const float*)d_in[11];

    char* w = (char*)d_ws;
    const size_t MB = 1ull << 20;
    _Float16* cw  = (_Float16*)(w);                 // [0,8) fp16 weights WQ|WK|WV|WO
    _Float16* ab  = (_Float16*)(w + 8 * MB);        // [8,16) attention out fp16
    _Float16* qb  = (_Float16*)(w + 16 * MB);
    _Float16* kbf = (_Float16*)(w + 24 * MB);
    _Float16* vtb = (_Float16*)(w + 32 * MB);
    unsigned int* mbits = (unsigned int*)(w + 40 * MB);

    conv_w<<<dim3(2048), dim3(256), 0, stream>>>(WQw, WKw, WVw, WOw, cw);
    pack_mask_k<<<dim3(1024), dim3(256), 0, stream>>>(mask, mbits);

    QkvArgs ga;
    ga.A0 = Q;   ga.A1 = Kin; ga.A2 = Vin;
    ga.b0 = WQb; ga.b1 = WKb; ga.b2 = WVb;
    ga.o0 = qb;  ga.o1 = kbf; ga.o2 = vtb;
    gemm_qkv<<<dim3(512, 3), dim3(256), 0, stream>>>(ga, cw);

    attn_fwd<<<dim3(1024), dim3(256), 0, stream>>>(qb, kbf, vtb, mbits, ab);

    gemm_out<<<dim3(512), dim3(256), 0, stream>>>(ab, cw + 3ull * D_MODEL * D_MODEL, WOb,
                                                  (float*)d_out);
}

// Round 10
// 146.492 us; speedup vs baseline: 2.2356x; 1.0382x over previous
//
#include <hip/hip_runtime.h>
#include <stdint.h>

#define D_MODEL 1024
#define NH 16
#define DKK 64
#define SEQ 2048
// softmax scale folded into Q projection: 0.125 * log2(e)
#define QSCALE 0.18033688011112042f

using half8 = __attribute__((ext_vector_type(8))) _Float16;
using half4 = __attribute__((ext_vector_type(4))) _Float16;
using half2v = __attribute__((ext_vector_type(2))) _Float16;
using fp16x2 = __attribute__((ext_vector_type(2))) __fp16;
using f32x4 = __attribute__((ext_vector_type(4))) float;
using f32x16 = __attribute__((ext_vector_type(16))) float;

__device__ __forceinline__ f32x4 fz4() { f32x4 v = {0.f, 0.f, 0.f, 0.f}; return v; }

// async global->LDS, 16B per lane; LDS dest = wave-uniform base + lane*16
__device__ __forceinline__ void gload16(const void* g, void* l) {
    __builtin_amdgcn_global_load_lds(
        (const __attribute__((address_space(1))) unsigned int*)g,
        (__attribute__((address_space(3))) unsigned int*)l, 16, 0, 0);
}

__device__ __forceinline__ half2v pk2(float a, float b) {
    fp16x2 t = __builtin_amdgcn_cvt_pkrtz(a, b);
    return __builtin_bit_cast(half2v, t);
}

__device__ __forceinline__ half4 pk4(float a, float b, float c, float d) {
    half2v lo = pk2(a, b);
    half2v hi = pk2(c, d);
    half4 r; r.x = lo.x; r.y = lo.y; r.z = hi.x; r.w = hi.y;
    return r;
}

// XCD-chunked swizzle
__device__ __forceinline__ int xswz(int bid, int n) {
    return (bid & 7) * (n >> 3) + (bid >> 3);
}

// ---------------- fp32 -> fp16 conversion: [WQ|WK|WV|WO|Q|K|V] ----------------
// 4M float4-chunks: [0,1M) = 4 weights (256K each), [1M,2M)=Q, [2M,3M)=K, [3M,4M)=V.
__global__ __launch_bounds__(256) void conv_all(const float* __restrict__ wq,
                                                const float* __restrict__ wk,
                                                const float* __restrict__ wv,
                                                const float* __restrict__ wo,
                                                const float* __restrict__ Q,
                                                const float* __restrict__ K,
                                                const float* __restrict__ V,
                                                _Float16* __restrict__ out) {
    int idx = blockIdx.x * 256 + threadIdx.x;     // 2048 blocks -> 524288 threads
#pragma unroll
    for (int k = 0; k < 8; ++k) {
        int c = idx + k * 524288;
        const float* src;
        int off;
        if (c < 1048576) {
            int w = c >> 18;
            src = (w == 0) ? wq : (w == 1) ? wk : (w == 2) ? wv : wo;
            off = c & 0x3ffff;
        } else {
            int j = (c >> 20) - 1;
            src = (j == 0) ? Q : (j == 1) ? K : V;
            off = c & 0xfffff;
        }
        float4 v = ((const float4*)src)[off];
        ((half4*)out)[c] = pk4(v.x, v.y, v.z, v.w);
    }
}

// ---------------- mask -> bitmask ----------------
__global__ __launch_bounds__(256) void pack_mask_k(const int* __restrict__ mask,
                                                   unsigned int* __restrict__ mbits) {
    int wid = threadIdx.x >> 6, lane = threadIdx.x & 63;
    int row = blockIdx.x * 4 + wid;
    const int* mrow = mask + (size_t)row * SEQ;
    unsigned int* orow = mbits + (size_t)row * (SEQ / 32);
    for (int it = 0; it < SEQ / 64; ++it) {
        int v = mrow[it * 64 + lane];
        unsigned long long bal = __ballot(v != 0);
        if (lane == 0)       orow[it * 2]     = (unsigned int)(bal & 0xffffffffull);
        else if (lane == 32) orow[it * 2 + 1] = (unsigned int)(bal >> 32);
    }
}

// ---------------- GEMM body: C[m][n] = A[m][:]·W[n][:] + bias[n], all-fp16 ----------------
// BM=64 BN=128 BK=64, dbuf LDS, A and B staged via global_load_lds (src pre-swizzled).
// omode: 0 = fp16 head-split [B,H,S,dk] (scaled); 1 = fp16 transposed [B,H,dk,S]; 2 = fp32 [M,N].
__device__ __forceinline__ void gemm_body(const _Float16* __restrict__ A,
                                          const _Float16* __restrict__ Wh,
                                          const float* __restrict__ bias,
                                          void* __restrict__ outp, int omode, float scale) {
    __shared__ __align__(16) _Float16 Asm[2][64 * 64];
    __shared__ __align__(16) _Float16 Bsm[2][128 * 64];
    const int tid = threadIdx.x;
    const int wg = xswz(blockIdx.x, 512);
    const int bm = wg >> 3, bn = wg & 7;
    const int wid = tid >> 6, lane = tid & 63;
    const int li = lane & 15, g = lane >> 4;
    const int wm = wid >> 1, wn = wid & 1;

    const int brow = wid * 32 + (lane >> 3);
    const char* bsrc = (const char*)(Wh + (size_t)(bn * 128 + brow) * D_MODEL)
                       + (((lane & 7) ^ (brow & 7)) * 16);
    const int bdst = wid * 32 * 128;
    const int arow = wid * 16 + (lane >> 3);
    const char* asrc = (const char*)(A + (size_t)(bm * 64 + arow) * D_MODEL)
                       + (((lane & 7) ^ (arow & 7)) * 16);
    const int adst = wid * 16 * 128;

    f32x4 acc[2][4];
#pragma unroll
    for (int i = 0; i < 2; ++i)
#pragma unroll
        for (int j = 0; j < 4; ++j) acc[i][j] = fz4();

    const int o0 = ((g << 4))      ^ ((li & 7) << 4);
    const int o1 = (64 + (g << 4)) ^ ((li & 7) << 4);
    const int abase = wm * 4096 + li * 128;
    const int bbase = wn * 8192 + li * 128;

    auto stage = [&](int it, int buf) {
        const char* bs = bsrc + it * 128;
        char* bd = (char*)&Bsm[buf][0] + bdst;
        gload16(bs,             bd);
        gload16(bs +  8 * 2048, bd + 1024);
        gload16(bs + 16 * 2048, bd + 2048);
        gload16(bs + 24 * 2048, bd + 3072);
        const char* as = asrc + it * 128;
        char* ad = (char*)&Asm[buf][0] + adst;
        gload16(as,            ad);
        gload16(as + 8 * 2048, ad + 1024);
    };

    stage(0, 0);
    __syncthreads();

    for (int it = 0; it < 16; ++it) {
        const int cur = it & 1;
        if (it + 1 < 16) stage(it + 1, cur ^ 1);
        const char* ab = (const char*)&Asm[cur][0];
        const char* bb = (const char*)&Bsm[cur][0];
#pragma unroll
        for (int s = 0; s < 2; ++s) {
            const int oS = s ? o1 : o0;
            half8 af0 = *(const half8*)(ab + abase + 0    + oS);
            half8 af1 = *(const half8*)(ab + abase + 2048 + oS);
            half8 bf[4];
#pragma unroll
            for (int nt = 0; nt < 4; ++nt)
                bf[nt] = *(const half8*)(bb + bbase + nt * 2048 + oS);
#pragma unroll
            for (int nt = 0; nt < 4; ++nt) {
                acc[0][nt] = __builtin_amdgcn_mfma_f32_16x16x32_f16(af0, bf[nt], acc[0][nt], 0, 0, 0);
                acc[1][nt] = __builtin_amdgcn_mfma_f32_16x16x32_f16(af1, bf[nt], acc[1][nt], 0, 0, 0);
            }
        }
        __syncthreads();
    }

#pragma unroll
    for (int nt = 0; nt < 4; ++nt) {
        int n = bn * 128 + wn * 64 + nt * 16 + li;
        float bv = bias[n];
#pragma unroll
        for (int mt = 0; mt < 2; ++mt) {
            if (omode == 1) {
                int s0 = bm * 64 + wm * 32 + mt * 16 + g * 4;
                int b = (bm * 64) >> 11;
                int h = n >> 6, d = n & 63;
                half4 hv = pk4(acc[mt][nt][0] + bv, acc[mt][nt][1] + bv,
                               acc[mt][nt][2] + bv, acc[mt][nt][3] + bv);
                *(half4*)((_Float16*)outp +
                          ((((size_t)(b * NH + h)) * DKK + d) * SEQ + (s0 & (SEQ - 1)))) = hv;
            } else {
#pragma unroll
                for (int r = 0; r < 4; ++r) {
                    int m = bm * 64 + wm * 32 + mt * 16 + g * 4 + r;
                    float val = (acc[mt][nt][r] + bv) * scale;
                    if (omode == 2) {
                        ((float*)outp)[(size_t)m * D_MODEL + n] = val;
                    } else {
                        int b = m >> 11, s = m & (SEQ - 1);
                        int h = n >> 6, d = n & 63;
                        ((_Float16*)outp)[(((size_t)(b * NH + h)) * SEQ + s) * DKK + d] =
                            (_Float16)val;
                    }
                }
            }
        }
    }
}

struct QkvArgs {
    const float *b0, *b1, *b2;
    _Float16 *o0, *o1, *o2;
};

__global__ __launch_bounds__(256) void gemm_qkv(const _Float16* __restrict__ Ah,
                                                const _Float16* __restrict__ cw,
                                                QkvArgs ga) {
    const int z = blockIdx.y;
    const _Float16* A  = Ah + (size_t)z * (D_MODEL * 4096);
    const float* bi = (z == 0) ? ga.b0 : (z == 1) ? ga.b1 : ga.b2;
    _Float16*    o  = (z == 0) ? ga.o0 : (z == 1) ? ga.o1 : ga.o2;
    gemm_body(A, cw + (size_t)z * D_MODEL * D_MODEL, bi, o,
              (z == 2) ? 1 : 0, (z == 0) ? QSCALE : 1.0f);
}

__global__ __launch_bounds__(256) void gemm_out(const _Float16* __restrict__ A,
                                                const _Float16* __restrict__ cw,
                                                const float* __restrict__ bias,
                                                float* __restrict__ out) {
    gemm_body(A, cw, bias, out, 2, 1.0f);
}

// ---------------- attention: 32x32 MFMA, in-register P, no P-LDS (unchanged r9) ----------------
__global__ __launch_bounds__(256, 4) void attn_fwd(const _Float16* __restrict__ q,
                                                   const _Float16* __restrict__ kk,
                                                   const _Float16* __restrict__ vt,
                                                   const unsigned int* __restrict__ mb,
                                                   _Float16* __restrict__ aout) {
    __shared__ __align__(16) char smem[32768];
    const int wg = xswz(blockIdx.x, 1024);
    const int qblk = wg & 31, bh = wg >> 5;
    const int b = bh >> 4, h = bh & 15;
    const int tid = threadIdx.x, wid = tid >> 6, lane = tid & 63;
    const int l31 = lane & 31, hi = lane >> 5;
    const int qh = wid & 1, kh = wid >> 1;     // wave -> (q-half, key-half)
    const _Float16* qp = q  + (size_t)bh * SEQ * DKK;
    const _Float16* kp = kk + (size_t)bh * SEQ * DKK;
    const _Float16* vp = vt + (size_t)bh * DKK * SEQ;
    const int qrow = qblk * 64 + qh * 32 + l31;

    half8 qf[4];
#pragma unroll
    for (int s = 0; s < 4; ++s)
        qf[s] = *(const half8*)(qp + (size_t)qrow * DKK + s * 16 + hi * 8);

    const int srow = wid * 16 + (lane >> 3);
    const int sswz = ((lane & 7) ^ (srow & 7)) * 16;
    const char* ksrc = (const char*)(kp + (size_t)srow * DKK) + sswz;
    const char* vsrc = (const char*)(vp + (size_t)srow * SEQ) + sswz;
    const int sdst = wid * 2048;

    auto stage = [&](int it, int buf) {
        const char* ks = ksrc + (size_t)it * 8192;
        const char* vs = vsrc + (size_t)it * 128;
        char* kd = smem + buf * 8192 + sdst;
        char* vd = smem + 16384 + buf * 8192 + sdst;
        gload16(ks,                       kd);
        gload16(ks + 8 * 128,             kd + 1024);
        gload16(vs,                       vd);
        gload16(vs + 8 * (size_t)SEQ * 2, vd + 1024);
    };

    f32x16 O0, O1;
#pragma unroll
    for (int j = 0; j < 16; ++j) { O0[j] = 0.f; O1[j] = 0.f; }
    float lsum = 0.f;

    const unsigned int* mrow = mb + (size_t)(b * SEQ + qrow) * (SEQ / 32);

    const int krow = kh * 32 + l31;
    const int kbase = krow * 128;
    const int krx = (krow & 7);
    const int v0row = l31;
    const int v1row = 32 + l31;

    stage(0, 0);
    __syncthreads();

    for (int it = 0; it < SEQ / 64; ++it) {
        const int cur = it & 1;
        if (it + 1 < SEQ / 64) stage(it + 1, cur ^ 1);
        const unsigned mw = mrow[it * 2 + kh] >> (hi * 4);

        f32x16 st;
#pragma unroll
        for (int j = 0; j < 16; ++j) st[j] = 0.f;
        const char* kb_ = smem + cur * 8192;
        __builtin_amdgcn_s_setprio(1);
#pragma unroll
        for (int s = 0; s < 4; ++s) {
            const int c = s * 2 + hi;
            half8 kf = *(const half8*)(kb_ + kbase + ((c ^ krx) << 4));
            st = __builtin_amdgcn_mfma_f32_32x32x16_f16(kf, qf[s], st, 0, 0, 0);
        }
        __builtin_amdgcn_s_setprio(0);

        unsigned w[8];
#pragma unroll
        for (int rq = 0; rq < 4; ++rq) {
            float e0 = __builtin_amdgcn_exp2f(st[rq * 4 + 0]);
            float e1 = __builtin_amdgcn_exp2f(st[rq * 4 + 1]);
            float e2 = __builtin_amdgcn_exp2f(st[rq * 4 + 2]);
            float e3 = __builtin_amdgcn_exp2f(st[rq * 4 + 3]);
            float p0 = ((mw >> (8 * rq + 0)) & 1u) ? e0 : 1.0f;
            float p1 = ((mw >> (8 * rq + 1)) & 1u) ? e1 : 1.0f;
            float p2 = ((mw >> (8 * rq + 2)) & 1u) ? e2 : 1.0f;
            float p3 = ((mw >> (8 * rq + 3)) & 1u) ? e3 : 1.0f;
            lsum += (p0 + p1) + (p2 + p3);
            w[2 * rq]     = __builtin_bit_cast(unsigned, pk2(p0, p1));
            w[2 * rq + 1] = __builtin_bit_cast(unsigned, pk2(p2, p3));
        }

        half8 pfrag[2];
#pragma unroll
        for (int s2 = 0; s2 < 2; ++s2) {
            unsigned a0 = w[s2 * 4 + 0], a1 = w[s2 * 4 + 1];
            unsigned a2 = w[s2 * 4 + 2], a3 = w[s2 * 4 + 3];
            unsigned t0 = (unsigned)__shfl_xor((int)(hi ? a0 : a2), 32);
            unsigned t1 = (unsigned)__shfl_xor((int)(hi ? a1 : a3), 32);
            uint4 f;
            f.x = hi ? t0 : a0;
            f.y = hi ? t1 : a1;
            f.z = hi ? a2 : t0;
            f.w = hi ? a3 : t1;
            pfrag[s2] = __builtin_bit_cast(half8, f);
        }

        const char* vb_ = smem + 16384 + cur * 8192;
        __builtin_amdgcn_s_setprio(1);
#pragma unroll
        for (int s2 = 0; s2 < 2; ++s2) {
            const int c = kh * 4 + s2 * 2 + hi;
            half8 vf0 = *(const half8*)(vb_ + v0row * 128 + ((c ^ (v0row & 7)) << 4));
            half8 vf1 = *(const half8*)(vb_ + v1row * 128 + ((c ^ (v1row & 7)) << 4));
            O0 = __builtin_amdgcn_mfma_f32_32x32x16_f16(vf0, pfrag[s2], O0, 0, 0, 0);
            O1 = __builtin_amdgcn_mfma_f32_32x32x16_f16(vf1, pfrag[s2], O1, 0, 0, 0);
        }
        __builtin_amdgcn_s_setprio(0);
        __syncthreads();
    }

    lsum += __shfl_xor(lsum, 32);

    const int SSTR = 36;
    float* scr = (float*)smem;
    float* lscr = (float*)(smem + 2 * 64 * SSTR * 4);
    if (kh == 1) {
        float* dst = scr + (size_t)qh * (64 * SSTR) + lane * SSTR;
#pragma unroll
        for (int j = 0; j < 4; ++j) {
            *(f32x4*)(dst + j * 4)      = *((f32x4*)&O0 + j);
            *(f32x4*)(dst + 16 + j * 4) = *((f32x4*)&O1 + j);
        }
        if (hi == 0) lscr[qh * 32 + l31] = lsum;
    }
    __syncthreads();
    if (kh == 0) {
        const float* src = scr + (size_t)qh * (64 * SSTR) + lane * SSTR;
#pragma unroll
        for (int j = 0; j < 16; ++j) { O0[j] += src[j]; O1[j] += src[16 + j]; }
        float inv = 1.0f / (lsum + lscr[qh * 32 + l31]);
        _Float16* orow = aout + ((size_t)(b * SEQ + qrow)) * D_MODEL + h * DKK + hi * 4;
#pragma unroll
        for (int rq = 0; rq < 4; ++rq) {
            *(half4*)(orow + 8 * rq) =
                pk4(O0[rq * 4 + 0] * inv, O0[rq * 4 + 1] * inv,
                    O0[rq * 4 + 2] * inv, O0[rq * 4 + 3] * inv);
            *(half4*)(orow + 32 + 8 * rq) =
                pk4(O1[rq * 4 + 0] * inv, O1[rq * 4 + 1] * inv,
                    O1[rq * 4 + 2] * inv, O1[rq * 4 + 3] * inv);
        }
    }
}

extern "C" void kernel_launch(void* const* d_in, const int* in_sizes, int n_in,
                              void* d_out, int out_size, void* d_ws, size_t ws_size,
                              hipStream_t stream) {
    const float* Q    = (const float*)d_in[0];
    const float* Kin  = (const float*)d_in[1];
    const float* Vin  = (const float*)d_in[2];
    const int*   mask = (const int*)d_in[3];
    const float* WQw = (const float*)d_in[4];
    const float* WQb = (const float*)d_in[5];
    const float* WKw = (const float*)d_in[6];
    const float* WKb = (const float*)d_in[7];
    const float* WVw = (const float*)d_in[8];
    const float* WVb = (const float*)d_in[9];
    const float* WOw = (const float*)d_in[10];
    const float* WOb = (const float*)d_in[11];

    char* w = (char*)d_ws;
    const size_t MB = 1ull << 20;
    // ws layout (57 MB):
    //  [0,8)   cw    fp16 weights WQ|WK|WV|WO
    //  [8,32)  Ah    fp16 Q|K|V inputs (Q region [8,16) reused as ab after gemm_qkv)
    //  [32,40) qb  [40,48) kbf  [48,56) vtb
    //  [56,57) mbits
    _Float16* cw  = (_Float16*)(w);
    _Float16* Ah  = (_Float16*)(w + 8 * MB);
    _Float16* ab  = (_Float16*)(w + 8 * MB);        // overlays Q-half of Ah (dead after gemm_qkv)
    _Float16* qb  = (_Float16*)(w + 32 * MB);
    _Float16* kbf = (_Float16*)(w + 40 * MB);
    _Float16* vtb = (_Float16*)(w + 48 * MB);
    unsigned int* mbits = (unsigned int*)(w + 56 * MB);

    conv_all<<<dim3(2048), dim3(256), 0, stream>>>(WQw, WKw, WVw, WOw, Q, Kin, Vin, cw);
    pack_mask_k<<<dim3(1024), dim3(256), 0, stream>>>(mask, mbits);

    QkvArgs ga;
    ga.b0 = WQb; ga.b1 = WKb; ga.b2 = WVb;
    ga.o0 = qb;  ga.o1 = kbf; ga.o2 = vtb;
    gemm_qkv<<<dim3(512, 3), dim3(256), 0, stream>>>(Ah, cw, ga);

    attn_fwd<<<dim3(1024), dim3(256), 0, stream>>>(qb, kbf, vtb, mbits, ab);

    gemm_out<<<dim3(512), dim3(256), 0, stream>>>(ab, cw + 3ull * D_MODEL * D_MODEL, WOb,
                                                  (float*)d_out);
}